// Round 8
// baseline (743.588 us; speedup 1.0000x reference)
//
#include <hip/hip_runtime.h>
#include <hip/hip_bf16.h>
#include <cmath>

#define B_ 2
#define H_ 8
#define S_ 2048
#define D_ 64
#define TQ 16
#define TK 64
#define KCHUNKS 8
#define TPC ((S_ / TK) / KCHUNKS)   // 4 k-tiles of 64 keys per chunk

typedef __bf16 bf16x8 __attribute__((ext_vector_type(8)));
typedef float  f32x4  __attribute__((ext_vector_type(4)));

// 272B rows = 17 x 16B units: odd word count staggers banks across rows.
#define SB_STRIDE 68

#define NK ((size_t)B_ * H_ * S_ * D_)   // 2,097,152 elements

// ---------------- prep 1: X -> bf16 hi/lo split (fp32-grade MFMA inputs) ----------------
__global__ __launch_bounds__(256)
void prep_k(const float* __restrict__ kg, __bf16* __restrict__ khi, __bf16* __restrict__ klo)
{
    const size_t i = ((size_t)blockIdx.x * 256 + threadIdx.x) * 8;
    float4 f0 = ((const float4*)(kg + i))[0];
    float4 f1 = ((const float4*)(kg + i))[1];
    float fv[8] = {f0.x, f0.y, f0.z, f0.w, f1.x, f1.y, f1.z, f1.w};
    bf16x8 hi, lo;
    #pragma unroll
    for (int j = 0; j < 8; ++j) {
        __bf16 h = (__bf16)fv[j];
        hi[j] = h;
        lo[j] = (__bf16)(fv[j] - (float)h);
    }
    *(bf16x8*)(khi + i) = hi;
    *(bf16x8*)(klo + i) = lo;
}

// prep 1b: Q -> SCALED bf16 hi/lo (scale folded in; split must happen on scaled value)
__global__ __launch_bounds__(256)
void prep_q(const float* __restrict__ qg, __bf16* __restrict__ qhi, __bf16* __restrict__ qlo)
{
    const float scale = 0.35355339059327373f;  // 1/sqrt(H=8) -- k.shape[1] trap!
    const size_t i = ((size_t)blockIdx.x * 256 + threadIdx.x) * 8;
    float4 f0 = ((const float4*)(qg + i))[0];
    float4 f1 = ((const float4*)(qg + i))[1];
    float fv[8] = {f0.x, f0.y, f0.z, f0.w, f1.x, f1.y, f1.z, f1.w};
    bf16x8 hi, lo;
    #pragma unroll
    for (int j = 0; j < 8; ++j) {
        float fs = fv[j] * scale;
        __bf16 h = (__bf16)fs;
        hi[j] = h;
        lo[j] = (__bf16)(fs - (float)h);
    }
    *(bf16x8*)(qhi + i) = hi;
    *(bf16x8*)(qlo + i) = lo;
}

// ---------------- prep 2: V -> bf16 transposed vt[b][h][d][s] ----------------
__global__ __launch_bounds__(256)
void prep_vt(const float* __restrict__ vg, __bf16* __restrict__ vt)
{
    __shared__ float tile[64][65];
    const int bh = blockIdx.x >> 5;   // 0..15 = b*H+h
    const int kt = blockIdx.x & 31;   // 64-key tile
    const int t  = threadIdx.x;
    {
        const int key = t >> 2, seg = t & 3;
        const float* src = vg + ((size_t)bh * S_ + kt * 64 + key) * D_ + seg * 16;
        #pragma unroll
        for (int i = 0; i < 4; ++i) {
            float4 f = ((const float4*)src)[i];
            tile[key][seg * 16 + i * 4 + 0] = f.x;
            tile[key][seg * 16 + i * 4 + 1] = f.y;
            tile[key][seg * 16 + i * 4 + 2] = f.z;
            tile[key][seg * 16 + i * 4 + 3] = f.w;
        }
    }
    __syncthreads();
    {
        const int d = t >> 2, seg = t & 3;
        bf16x8 o0, o1;
        #pragma unroll
        for (int j = 0; j < 8; ++j) o0[j] = (__bf16)tile[seg * 16 + j][d];
        #pragma unroll
        for (int j = 0; j < 8; ++j) o1[j] = (__bf16)tile[seg * 16 + 8 + j][d];
        __bf16* dst = vt + ((size_t)bh * D_ + d) * S_ + kt * 64 + seg * 16;
        *(bf16x8*)dst       = o0;
        *((bf16x8*)dst + 1) = o1;
    }
}

// ---------------- main fused kernel ----------------
// STRUCTURE (round 8): the axis=1 softmax couples HEADS, not keys. So in the QK
// phase each wave owns a 16-KEY SLAB x ALL 8 HEADS: the MFMA C-layout puts
// (q=quad*4+r, k=n16) in one lane for every head -> max/exp/sum across heads is
// pure lane-local register math. This deletes the block-wide QK->softmax join
// (rounds 0-7 all convoyed on it, pinned at ~260us). One barrier-pair remains
// per iteration (att handoff to PV). Q hi/lo comes pre-split from prep_q so no
// 32-reg Q residency: peak live ~110 regs -> 4 blocks/CU, no spill (r7 lesson).
__global__ __launch_bounds__(256, 4)
void attn_fused(const __bf16* __restrict__ qhi_g, const __bf16* __restrict__ qlo_g,
                const __bf16* __restrict__ khi_g, const __bf16* __restrict__ klo_g,
                const __bf16* __restrict__ vt_g,  const int* __restrict__ maskg,
                float* __restrict__ zout, float* __restrict__ attout)
{
    // fp32 POST-softmax att tiles (PV converts to bf16 in-register)
    __shared__ __align__(16) float sbuf[H_][TQ][SB_STRIDE];   // 34,816 B -> 4 blocks/CU

    const int tid  = threadIdx.x;
    const int lane = tid & 63;
    const int wave = tid >> 6;      // phase A: key-slab; phase B: head-pair
    const int n16  = lane & 15;
    const int quad = lane >> 4;

    // ROUND-0 grid mapping (measured-good): chunk in HIGH bits -> all 8 chunk
    // partials of a q-tile land on the same XCD (bi%8 invariant in chunk):
    // z atomics L2-local, K/V hot set survives L2.
    const int bi    = blockIdx.x;
    const int b     = bi & 1;
    const int qt    = (bi >> 1) & 127;
    const int chunk = bi >> 8;
    const int q0    = qt * TQ;

    f32x4 acc[2][4];
    #pragma unroll
    for (int hh = 0; hh < 2; ++hh)
        #pragma unroll
        for (int d = 0; d < 4; ++d)
            acc[hh][d] = (f32x4){0.f, 0.f, 0.f, 0.f};

    const int myk_off = wave * 16 + n16;            // key within 64-key tile
    // mask[b][q0+quad*4+r][chunk_base + kt*TK + myk_off]
    const int* mptr = maskg + (size_t)(b * S_ + q0 + quad * 4) * S_
                      + chunk * (TK * TPC) + myk_off;

    int mcur[4];
    #pragma unroll
    for (int r = 0; r < 4; ++r) mcur[r] = mptr[(size_t)r * S_];   // kt = 0

    for (int kt = 0; kt < TPC; ++kt) {
        const int k0 = chunk * (TK * TPC) + kt * TK;

        // prefetch next iteration's mask (4 scalar loads, full iter of slack)
        const int kn = (kt + 1 < TPC) ? (kt + 1) : kt;
        int mnext[4];
        #pragma unroll
        for (int r = 0; r < 4; ++r) mnext[r] = mptr[(size_t)kn * TK + (size_t)r * S_];

        __syncthreads();   // (b3) previous iteration's PV done reading sbuf

        // ---- Phase A: QK^T, this wave's 16-key slab x ALL 8 heads ----
        f32x4 sc[H_];
        #pragma unroll
        for (int h = 0; h < H_; ++h) {
            const size_t qrow = ((size_t)(b * H_ + h) * S_ + q0 + n16) * D_ + quad * 8;
            const size_t krow = ((size_t)(b * H_ + h) * S_ + k0 + wave * 16 + n16) * D_
                                + quad * 8;
            f32x4 cc = (f32x4){0.f, 0.f, 0.f, 0.f};
            #pragma unroll
            for (int kk = 0; kk < 2; ++kk) {
                bf16x8 qh = *(const bf16x8*)(qhi_g + qrow + kk * 32);
                bf16x8 ql = *(const bf16x8*)(qlo_g + qrow + kk * 32);
                bf16x8 kh = *(const bf16x8*)(khi_g + krow + kk * 32);
                bf16x8 kl = *(const bf16x8*)(klo_g + krow + kk * 32);
                cc = __builtin_amdgcn_mfma_f32_16x16x32_bf16(qh, kh, cc, 0, 0, 0);
                cc = __builtin_amdgcn_mfma_f32_16x16x32_bf16(ql, kh, cc, 0, 0, 0);
                cc = __builtin_amdgcn_mfma_f32_16x16x32_bf16(qh, kl, cc, 0, 0, 0);
            }
            sc[h] = cc;   // sc[h][r] = score(q=quad*4+r, k=k0+myk_off, head h)
        }

        // ---- LANE-LOCAL softmax across heads (vector index j == r == q-row) ----
        {
            f32x4 mx = sc[0];
            #pragma unroll
            for (int h = 1; h < H_; ++h)
                #pragma unroll
                for (int j = 0; j < 4; ++j) mx[j] = fmaxf(mx[j], sc[h][j]);
            f32x4 sum = (f32x4){0.f, 0.f, 0.f, 0.f};
            #pragma unroll
            for (int h = 0; h < H_; ++h)
                #pragma unroll
                for (int j = 0; j < 4; ++j) {
                    sc[h][j] = __expf(sc[h][j] - mx[j]);
                    sum[j] += sc[h][j];
                }
            f32x4 inv;
            #pragma unroll
            for (int j = 0; j < 4; ++j) inv[j] = 1.0f / sum[j];
            #pragma unroll
            for (int h = 0; h < H_; ++h) {
                #pragma unroll
                for (int j = 0; j < 4; ++j) {
                    // all-heads-masked => ties => uniform softmax = 1/8
                    const float a = (mcur[j] == 0) ? 0.125f : sc[h][j] * inv[j];
                    // att fp32 -> global (4B; 16 n16-lanes give 64B segments)
                    attout[((size_t)((b * H_ + h) * S_ + q0 + quad * 4 + j)) * S_
                           + k0 + myk_off] = a;
                    // post-softmax fp32 att -> LDS for PV (2-way banks max)
                    sbuf[h][quad * 4 + j][myk_off] = a;
                }
            }
        }

        __syncthreads();   // (b1) att visible to PV waves

        // ---- Phase B: PV, wave = heads 2w,2w+1; A-frag f32->bf16 in-register ----
        #pragma unroll
        for (int hh = 0; hh < 2; ++hh) {
            const int h = wave * 2 + hh;
            #pragma unroll
            for (int kk = 0; kk < 2; ++kk) {
                const float* ap = &sbuf[h][n16][kk * 32 + quad * 8];
                f32x4 a0 = *(const f32x4*)ap;
                f32x4 a1 = *(const f32x4*)(ap + 4);
                bf16x8 af;
                #pragma unroll
                for (int j = 0; j < 4; ++j) {
                    af[j]     = (__bf16)a0[j];
                    af[4 + j] = (__bf16)a1[j];
                }
                #pragma unroll
                for (int dsb = 0; dsb < 4; ++dsb) {
                    bf16x8 bv = *(const bf16x8*)(vt_g
                        + ((size_t)(b * H_ + h) * D_ + dsb * 16 + n16) * S_
                        + k0 + kk * 32 + quad * 8);
                    acc[hh][dsb] = __builtin_amdgcn_mfma_f32_16x16x32_bf16(af, bv, acc[hh][dsb], 0, 0, 0);
                }
            }
        }

        #pragma unroll
        for (int r = 0; r < 4; ++r) mcur[r] = mnext[r];
    }

    // ---- epilogue: accumulate partial z across k-chunks via device atomics ----
    // (all 8 chunk-partials of a q-tile map to the same XCD -> L2-local atomics)
    #pragma unroll
    for (int hh = 0; hh < 2; ++hh) {
        const int h = wave * 2 + hh;
        #pragma unroll
        for (int dsb = 0; dsb < 4; ++dsb)
            #pragma unroll
            for (int r = 0; r < 4; ++r)
                atomicAdd(&zout[(size_t)((b * H_ + h) * S_ + q0 + quad * 4 + r) * D_
                                + dsb * 16 + n16],
                          acc[hh][dsb][r]);
    }
}

extern "C" void kernel_launch(void* const* d_in, const int* in_sizes, int n_in,
                              void* d_out, int out_size, void* d_ws, size_t ws_size,
                              hipStream_t stream) {
    const float* q    = (const float*)d_in[0];
    const float* k    = (const float*)d_in[1];
    const float* v    = (const float*)d_in[2];
    const int*   mask = (const int*)d_in[3];
    float* z   = (float*)d_out;
    float* att = (float*)d_out + NK;   // outputs: (z, att_score)

    // workspace: khi | klo | vt | qhi | qlo  (bf16 each, NK elements) = 21 MB
    __bf16* khi = (__bf16*)d_ws;
    __bf16* klo = khi + NK;
    __bf16* vt  = klo + NK;
    __bf16* qhi = vt  + NK;
    __bf16* qlo = qhi + NK;

    prep_k <<<dim3(NK / (256 * 8)), dim3(256), 0, stream>>>(k, khi, klo);
    prep_q <<<dim3(NK / (256 * 8)), dim3(256), 0, stream>>>(q, qhi, qlo);
    prep_vt<<<dim3(B_ * H_ * (S_ / 64)), dim3(256), 0, stream>>>(v, vt);

    // z accumulated atomically across 8 k-chunks -> must start at zero
    hipMemsetAsync(z, 0, NK * sizeof(float), stream);

    attn_fused<<<dim3(KCHUNKS * B_ * (S_ / TQ)), dim3(256), 0, stream>>>(
        qhi, qlo, khi, klo, vt, mask, z, att);
}